// Round 13
// baseline (516.651 us; speedup 1.0000x reference)
//
#include <hip/hip_runtime.h>

// AffinityPropagate (CSPN): B=8, C=32, H=W=256, K=3, prop_time=16.
// R12: attack weight-read amplification (the L2-bandwidth limiter).
// CPB 2->8: each weight row-set load is amortized over 8 channels
// (wgt held in VGPRs across the channel loop). STRIP 4 keeps mid at 48 KB.
// Weight L2 traffic: ~627 MB -> ~110 MB per dispatch. Plain 3D grid (R11's
// XCD remap was neutral). Planar weights + shfl halos kept (R9).

#define B_ 8
#define C_ 32
#define H_ 256
#define W_ 256
#define STRIP 4
#define CPB 8
#define MIDR (STRIP + 2)

// Planar weights: wts[((b*9)+j)*H*W + h*W + w]
__global__ __launch_bounds__(256)
void prep_weights_kernel(const float* __restrict__ guided,
                         const float* __restrict__ depth,
                         float* __restrict__ wts,
                         int total /* B*H*W */) {
    int idx = blockIdx.x * 256 + threadIdx.x;
    if (idx >= total) return;
    int b  = idx >> 16;        // H*W = 65536
    int hw = idx & 0xFFFF;
    const float* gp = guided + (((size_t)b * 8) << 16) + hw;
    float g[8];
    float m = -3.4e38f;
#pragma unroll
    for (int j = 0; j < 8; j++) { g[j] = gp[(size_t)j << 16]; m = fmaxf(m, g[j]); }
    float s = 0.f;
#pragma unroll
    for (int j = 0; j < 8; j++) { g[j] = expf(g[j] - m); s += g[j]; }
    float inv = 1.0f / s;
    float d = depth[(((size_t)b) << 16) + hw];
    bool fixed = d > 0.f;   // sign(depth) is 0/1 (depth >= 0)
    float* wp = wts + (((size_t)b * 9) << 16) + hw;
#pragma unroll
    for (int j = 0; j < 9; j++) {
        float v;
        if (j == 4) v = fixed ? 1.f : 0.f;            // center
        else        v = fixed ? 0.f : g[j - (j > 4 ? 1 : 0)] * inv;
        wp[(size_t)j << 16] = v;
    }
}

// acc[k] += wgt[3i+j][k] * rb[i][k+j]  — same fmaf order as R3/R4/R9 (passed).
__device__ __forceinline__ void stencil4(const float wgt[9][4],
                                         const float rb[3][6],
                                         float acc[4]) {
#pragma unroll
    for (int i = 0; i < 3; ++i)
#pragma unroll
        for (int j = 0; j < 3; ++j)
#pragma unroll
            for (int k = 0; k < 4; ++k)
                acc[k] = fmaf(wgt[i * 3 + j][k], rb[i][k + j], acc[k]);
}

// Two fused propagation steps. Block (64,4): one wave == one full 256-wide
// row (64 lanes x 4 px). Halos via wave shfl (no scalar loads, 0 conflicts).
__global__ __launch_bounds__(256)
void prop2_kernel(const float* __restrict__ xin,
                  const float* __restrict__ wts,
                  float* __restrict__ xout) {
    __shared__ float mid[CPB][MIDR][W_];   // 48 KB
    const int tx = threadIdx.x;            // 0..63
    const int ty = threadIdx.y;            // 0..3
    const int h0 = blockIdx.x * STRIP;
    const int c0 = blockIdx.y * CPB;
    const int b  = blockIdx.z;
    const int w0 = tx * 4;
    const size_t plane = (size_t)H_ * W_;
    const bool hasL = (tx > 0), hasR = (tx < 63);

    // ---- Phase 1: step-1 on rows h0-1 .. h0+STRIP, into LDS ----
    for (int rr = ty; rr < MIDR; rr += 4) {
        const int r = h0 - 1 + rr;
        if (r < 0 || r >= H_) {
            float4 z = {0.f, 0.f, 0.f, 0.f};
#pragma unroll
            for (int c = 0; c < CPB; ++c)
                *reinterpret_cast<float4*>(&mid[c][rr][w0]) = z;
            continue;
        }
        // planar weights: 9 fully-coalesced float4 loads, amortized over
        // CPB=8 channels below
        const float* wp = wts + (size_t)b * 9 * plane + (size_t)r * W_ + w0;
        float wgt[9][4];
#pragma unroll
        for (int j = 0; j < 9; ++j) {
            float4 v = *reinterpret_cast<const float4*>(wp + j * plane);
            wgt[j][0] = v.x; wgt[j][1] = v.y; wgt[j][2] = v.z; wgt[j][3] = v.w;
        }
#pragma unroll
        for (int c = 0; c < CPB; ++c) {
            const float* xc = xin + ((size_t)b * C_ + (c0 + c)) * plane;
            float rb[3][6];
#pragma unroll
            for (int i = 0; i < 3; ++i) {
                int row = r - 1 + i;
                if (row >= 0 && row < H_) {
                    float4 v = *reinterpret_cast<const float4*>(
                        xc + (size_t)row * W_ + w0);
                    float lh = __shfl_up(v.w, 1);
                    float rhv = __shfl_down(v.x, 1);
                    rb[i][0] = hasL ? lh : 0.f;
                    rb[i][1] = v.x; rb[i][2] = v.y; rb[i][3] = v.z; rb[i][4] = v.w;
                    rb[i][5] = hasR ? rhv : 0.f;
                } else {
#pragma unroll
                    for (int t = 0; t < 6; ++t) rb[i][t] = 0.f;
                }
            }
            float acc[4] = {0.f, 0.f, 0.f, 0.f};
            stencil4(wgt, rb, acc);
            float4 o = {acc[0], acc[1], acc[2], acc[3]};
            *reinterpret_cast<float4*>(&mid[c][rr][w0]) = o;
        }
    }
    __syncthreads();

    // ---- Phase 2: step-2 on rows h0 .. h0+STRIP-1, LDS -> global ----
    for (int rr = ty; rr < STRIP; rr += 4) {
        const int r = h0 + rr;
        const float* wp = wts + (size_t)b * 9 * plane + (size_t)r * W_ + w0;
        float wgt[9][4];
#pragma unroll
        for (int j = 0; j < 9; ++j) {
            float4 v = *reinterpret_cast<const float4*>(wp + j * plane);
            wgt[j][0] = v.x; wgt[j][1] = v.y; wgt[j][2] = v.z; wgt[j][3] = v.w;
        }
#pragma unroll
        for (int c = 0; c < CPB; ++c) {
            float rb[3][6];
#pragma unroll
            for (int i = 0; i < 3; ++i) {
                // mid index rr+i corresponds to global row r-1+i
                float4 v = *reinterpret_cast<const float4*>(&mid[c][rr + i][w0]);
                float lh = __shfl_up(v.w, 1);
                float rhv = __shfl_down(v.x, 1);
                rb[i][0] = hasL ? lh : 0.f;
                rb[i][1] = v.x; rb[i][2] = v.y; rb[i][3] = v.z; rb[i][4] = v.w;
                rb[i][5] = hasR ? rhv : 0.f;
            }
            float acc[4] = {0.f, 0.f, 0.f, 0.f};
            stencil4(wgt, rb, acc);
            float4 o = {acc[0], acc[1], acc[2], acc[3]};
            *reinterpret_cast<float4*>(xout + ((size_t)b * C_ + (c0 + c)) * plane +
                                       (size_t)r * W_ + w0) = o;
        }
    }
}

extern "C" void kernel_launch(void* const* d_in, const int* in_sizes, int n_in,
                              void* d_out, int out_size, void* d_ws, size_t ws_size,
                              hipStream_t stream) {
    const float* x      = (const float*)d_in[0];
    const float* guided = (const float*)d_in[1];
    const float* depth  = (const float*)d_in[2];
    // d_in[3] = prop_time; fixed to 16 by setup_inputs.
    const int FUSED_STEPS = 8;   // 16 propagation steps, 2 per kernel

    float* xbuf = (float*)d_ws;                                   // 64 MB
    float* wts  = (float*)((char*)d_ws +
                           (size_t)B_ * C_ * H_ * W_ * sizeof(float)); // 18.9 MB
    float* out  = (float*)d_out;

    int total = B_ * H_ * W_;
    hipLaunchKernelGGL(prep_weights_kernel, dim3((total + 255) / 256), dim3(256),
                       0, stream, guided, depth, wts, total);

    dim3 grid(H_ / STRIP, C_ / CPB, B_), block(64, 4, 1);
    const float* src = x;
    for (int t = 0; t < FUSED_STEPS; ++t) {
        float* dst = (t == FUSED_STEPS - 1) ? out : ((t % 2 == 0) ? xbuf : out);
        hipLaunchKernelGGL(prop2_kernel, grid, block, 0, stream,
                           src, wts, dst);
        src = dst;
    }
}

// Round 14
// 358.794 us; speedup vs baseline: 1.4400x; 1.4400x over previous
//
#include <hip/hip_runtime.h>

// AffinityPropagate (CSPN): B=8, C=32, H=W=256, K=3, prop_time=16.
// R13: temporal-wavefront streaming pipeline. T=4 steps per dispatch:
// wave s computes step s+1 of row f-2s at front f (lag-2 skew). Per-step
// intermediates in LDS rings of 4 rows (race-free by mod-4 slot disjointness,
// one barrier per front). x read once + written once per 4 steps.
// 16 steps = 4 dispatches (was 8). Planar weights + shfl halos kept (R9).

#define B_ 8
#define C_ 32
#define H_ 256
#define W_ 256
#define T_ 4
#define CPB 4
#define CHUNK 32
#define NFRONT (CHUNK + 3 * (T_ - 1))   // 41 fronts

// Planar weights: wts[((b*9)+j)*H*W + h*W + w]
__global__ __launch_bounds__(256)
void prep_weights_kernel(const float* __restrict__ guided,
                         const float* __restrict__ depth,
                         float* __restrict__ wts,
                         int total /* B*H*W */) {
    int idx = blockIdx.x * 256 + threadIdx.x;
    if (idx >= total) return;
    int b  = idx >> 16;        // H*W = 65536
    int hw = idx & 0xFFFF;
    const float* gp = guided + (((size_t)b * 8) << 16) + hw;
    float g[8];
    float m = -3.4e38f;
#pragma unroll
    for (int j = 0; j < 8; j++) { g[j] = gp[(size_t)j << 16]; m = fmaxf(m, g[j]); }
    float s = 0.f;
#pragma unroll
    for (int j = 0; j < 8; j++) { g[j] = expf(g[j] - m); s += g[j]; }
    float inv = 1.0f / s;
    float d = depth[(((size_t)b) << 16) + hw];
    bool fixed = d > 0.f;   // sign(depth) is 0/1 (depth >= 0)
    float* wp = wts + (((size_t)b * 9) << 16) + hw;
#pragma unroll
    for (int j = 0; j < 9; j++) {
        float v;
        if (j == 4) v = fixed ? 1.f : 0.f;            // center
        else        v = fixed ? 0.f : g[j - (j > 4 ? 1 : 0)] * inv;
        wp[(size_t)j << 16] = v;
    }
}

__device__ __forceinline__ float4 zero4() { return make_float4(0.f, 0.f, 0.f, 0.f); }

__device__ __forceinline__ float4 ldxrow(const float* xc, int row, int w0) {
    if (row < 0 || row >= H_) return zero4();
    return *reinterpret_cast<const float4*>(xc + (size_t)row * W_ + w0);
}

// acc[k] += wgt[3i+j][k] * rb[i][k+j]  — same fmaf order as R3..R12 (passed).
__device__ __forceinline__ void stencil4(const float wgt[9][4],
                                         const float rb[3][6],
                                         float acc[4]) {
#pragma unroll
    for (int i = 0; i < 3; ++i)
#pragma unroll
        for (int j = 0; j < 3; ++j)
#pragma unroll
            for (int k = 0; k < 4; ++k)
                acc[k] = fmaf(wgt[i * 3 + j][k], rb[i][k + j], acc[k]);
}

__device__ __forceinline__ void mkrb(float4 v, bool hasL, bool hasR, float rbrow[6]) {
    float lh = __shfl_up(v.w, 1);
    float rh = __shfl_down(v.x, 1);
    rbrow[0] = hasL ? lh : 0.f;
    rbrow[1] = v.x; rbrow[2] = v.y; rbrow[3] = v.z; rbrow[4] = v.w;
    rbrow[5] = hasR ? rh : 0.f;
}

// Block (64,4): wave s == pipeline stage s (step s+1). One wave = one full
// 256-wide row (64 lanes x 4 px), shfl halos. Rings: 4-row ring per step.
__global__ __launch_bounds__(256)
void prop_stream_kernel(const float* __restrict__ xin,
                        const float* __restrict__ wts,
                        float* __restrict__ xout) {
    __shared__ float ring[T_ - 1][4][CPB][W_];   // 3*4*4*256*4B = 48 KB
    const int tx = threadIdx.x;    // 0..63
    const int s  = threadIdx.y;    // 0..T_-1 (pipeline stage)
    const int h0 = blockIdx.x * CHUNK;
    const int c0 = blockIdx.y * CPB;
    const int b  = blockIdx.z;
    const int w0 = tx * 4;
    const size_t plane = (size_t)H_ * W_;
    const bool hasL = (tx > 0), hasR = (tx < 63);
    const int f_start = h0 - (T_ - 1);
    const int vfront  = f_start + 3 * s;   // first front with valid inputs

    const float* xb = xin + ((size_t)b * C_ + c0) * plane;
    const float* wb = wts + (size_t)b * 9 * plane;

    // wave-0 x register rotation: rows f-1, f held; f+1 loaded per front
    float4 xm[CPB], xc[CPB];
    if (s == 0) {
#pragma unroll
        for (int c = 0; c < CPB; ++c) {
            xm[c] = ldxrow(xb + c * plane, f_start - 1, w0);
            xc[c] = ldxrow(xb + c * plane, f_start,     w0);
        }
    }

    for (int f = f_start; f < f_start + NFRONT; ++f) {
        const int q = f - 2 * s;                 // row this wave produces
        const bool rowok = (q >= 0) && (q < H_);
        const bool val = rowok && (f >= vfront); // inputs fully valid

        float wgt[9][4];
        if (val) {
            const float* wp = wb + (size_t)q * W_ + w0;
#pragma unroll
            for (int j = 0; j < 9; ++j) {
                float4 v = *reinterpret_cast<const float4*>(wp + j * plane);
                wgt[j][0] = v.x; wgt[j][1] = v.y; wgt[j][2] = v.z; wgt[j][3] = v.w;
            }
        }

        if (s == 0) {
            // stage 1: inputs from global x (register-rotated window)
#pragma unroll
            for (int c = 0; c < CPB; ++c) {
                float4 xp = ldxrow(xb + c * plane, q + 1, w0);
                float acc[4] = {0.f, 0.f, 0.f, 0.f};
                if (val) {
                    float rb[3][6];
                    mkrb(xm[c], hasL, hasR, rb[0]);
                    mkrb(xc[c], hasL, hasR, rb[1]);
                    mkrb(xp,    hasL, hasR, rb[2]);
                    stencil4(wgt, rb, acc);
                }
                xm[c] = xc[c]; xc[c] = xp;       // advance EVERY front
                *reinterpret_cast<float4*>(&ring[0][q & 3][c][w0]) =
                    make_float4(acc[0], acc[1], acc[2], acc[3]);
            }
        } else {
            // stages 2..T: inputs from ring[s-1], rows q-1..q+1
#pragma unroll
            for (int c = 0; c < CPB; ++c) {
                float acc[4] = {0.f, 0.f, 0.f, 0.f};
                if (val) {
                    float rb[3][6];
#pragma unroll
                    for (int i = 0; i < 3; ++i) {
                        int p = q - 1 + i;
                        float4 v = (p >= 0 && p < H_)
                            ? *reinterpret_cast<const float4*>(&ring[s - 1][p & 3][c][w0])
                            : zero4();
                        mkrb(v, hasL, hasR, rb[i]);
                    }
                    stencil4(wgt, rb, acc);
                }
                if (s < T_ - 1) {
                    // unconditional write (zeros when invalid/out-of-range)
                    *reinterpret_cast<float4*>(&ring[s][q & 3][c][w0]) =
                        make_float4(acc[0], acc[1], acc[2], acc[3]);
                } else if (val && q >= h0 && q < h0 + CHUNK) {
                    *reinterpret_cast<float4*>(xout + ((size_t)b * C_ + (c0 + c)) * plane +
                                               (size_t)q * W_ + w0) =
                        make_float4(acc[0], acc[1], acc[2], acc[3]);
                }
            }
        }
        __syncthreads();   // front advance: all writes visible to next front
    }
}

extern "C" void kernel_launch(void* const* d_in, const int* in_sizes, int n_in,
                              void* d_out, int out_size, void* d_ws, size_t ws_size,
                              hipStream_t stream) {
    const float* x      = (const float*)d_in[0];
    const float* guided = (const float*)d_in[1];
    const float* depth  = (const float*)d_in[2];
    // d_in[3] = prop_time; fixed to 16 by setup_inputs.
    const int DISPATCHES = 4;    // 16 steps, T_=4 per dispatch

    float* xbuf = (float*)d_ws;                                   // 64 MB
    float* wts  = (float*)((char*)d_ws +
                           (size_t)B_ * C_ * H_ * W_ * sizeof(float)); // 18.9 MB
    float* out  = (float*)d_out;

    int total = B_ * H_ * W_;
    hipLaunchKernelGGL(prep_weights_kernel, dim3((total + 255) / 256), dim3(256),
                       0, stream, guided, depth, wts, total);

    dim3 grid(H_ / CHUNK, C_ / CPB, B_), block(64, T_, 1);
    const float* src = x;
    for (int t = 0; t < DISPATCHES; ++t) {
        float* dst = (t == DISPATCHES - 1) ? out : ((t % 2 == 0) ? xbuf : out);
        hipLaunchKernelGGL(prop_stream_kernel, grid, block, 0, stream,
                           src, wts, dst);
        src = dst;
    }
}

// Round 15
// 325.116 us; speedup vs baseline: 1.5891x; 1.1036x over previous
//
#include <hip/hip_runtime.h>

// AffinityPropagate (CSPN): B=8, C=32, H=W=256, K=3, prop_time=16.
// R14: R13 streaming pipeline + software prefetch. Per front, the NEXT
// front's weight row (9 float4, clamped) and stage-0 x row are issued
// BEFORE the barrier so their ~300-500cy L2/LLC latency hides under the
// barrier + next front's compute (compiler can't hoist loads across
// __syncthreads itself). Ring rows padded +4 floats to probe the 8.5M
// bank-conflict counter. Registers are free (occupancy is LDS-bound).

#define B_ 8
#define C_ 32
#define H_ 256
#define W_ 256
#define T_ 4
#define CPB 4
#define CHUNK 32
#define NFRONT (CHUNK + 3 * (T_ - 1))   // 41 fronts
#define WP_ (W_ + 4)                    // padded ring row

// Planar weights: wts[((b*9)+j)*H*W + h*W + w]
__global__ __launch_bounds__(256)
void prep_weights_kernel(const float* __restrict__ guided,
                         const float* __restrict__ depth,
                         float* __restrict__ wts,
                         int total /* B*H*W */) {
    int idx = blockIdx.x * 256 + threadIdx.x;
    if (idx >= total) return;
    int b  = idx >> 16;        // H*W = 65536
    int hw = idx & 0xFFFF;
    const float* gp = guided + (((size_t)b * 8) << 16) + hw;
    float g[8];
    float m = -3.4e38f;
#pragma unroll
    for (int j = 0; j < 8; j++) { g[j] = gp[(size_t)j << 16]; m = fmaxf(m, g[j]); }
    float s = 0.f;
#pragma unroll
    for (int j = 0; j < 8; j++) { g[j] = expf(g[j] - m); s += g[j]; }
    float inv = 1.0f / s;
    float d = depth[(((size_t)b) << 16) + hw];
    bool fixed = d > 0.f;   // sign(depth) is 0/1 (depth >= 0)
    float* wp = wts + (((size_t)b * 9) << 16) + hw;
#pragma unroll
    for (int j = 0; j < 9; j++) {
        float v;
        if (j == 4) v = fixed ? 1.f : 0.f;            // center
        else        v = fixed ? 0.f : g[j - (j > 4 ? 1 : 0)] * inv;
        wp[(size_t)j << 16] = v;
    }
}

__device__ __forceinline__ float4 zero4() { return make_float4(0.f, 0.f, 0.f, 0.f); }

__device__ __forceinline__ float4 ldxrow(const float* xc, int row, int w0) {
    if (row < 0 || row >= H_) return zero4();
    return *reinterpret_cast<const float4*>(xc + (size_t)row * W_ + w0);
}

// acc[k] += wgt[3i+j][k] * rb[i][k+j]  — same fmaf order as R3..R13 (passed).
__device__ __forceinline__ void stencil4(const float wgt[9][4],
                                         const float rb[3][6],
                                         float acc[4]) {
#pragma unroll
    for (int i = 0; i < 3; ++i)
#pragma unroll
        for (int j = 0; j < 3; ++j)
#pragma unroll
            for (int k = 0; k < 4; ++k)
                acc[k] = fmaf(wgt[i * 3 + j][k], rb[i][k + j], acc[k]);
}

__device__ __forceinline__ void mkrb(float4 v, bool hasL, bool hasR, float rbrow[6]) {
    float lh = __shfl_up(v.w, 1);
    float rh = __shfl_down(v.x, 1);
    rbrow[0] = hasL ? lh : 0.f;
    rbrow[1] = v.x; rbrow[2] = v.y; rbrow[3] = v.z; rbrow[4] = v.w;
    rbrow[5] = hasR ? rh : 0.f;
}

// Block (64,4): wave s == pipeline stage s (step s+1). One wave = one full
// 256-wide row (64 lanes x 4 px), shfl halos. Rings: 4-row ring per step.
__global__ __launch_bounds__(256)
void prop_stream_kernel(const float* __restrict__ xin,
                        const float* __restrict__ wts,
                        float* __restrict__ xout) {
    __shared__ float ring[T_ - 1][4][CPB][WP_];   // ~50 KB
    const int tx = threadIdx.x;    // 0..63
    const int s  = threadIdx.y;    // 0..T_-1 (pipeline stage)
    const int h0 = blockIdx.x * CHUNK;
    const int c0 = blockIdx.y * CPB;
    const int b  = blockIdx.z;
    const int w0 = tx * 4;
    const size_t plane = (size_t)H_ * W_;
    const bool hasL = (tx > 0), hasR = (tx < 63);
    const int f_start = h0 - (T_ - 1);
    const int vfront  = f_start + 3 * s;   // first front with valid inputs

    const float* xb = xin + ((size_t)b * C_ + c0) * plane;
    const float* wb = wts + (size_t)b * 9 * plane;

    // stage-0 x register window: rows q-1, q, q+1 (q = f for s=0)
    float4 xm[CPB], xc[CPB], xp[CPB];
    if (s == 0) {
#pragma unroll
        for (int c = 0; c < CPB; ++c) {
            xm[c] = ldxrow(xb + c * plane, f_start - 1, w0);
            xc[c] = ldxrow(xb + c * plane, f_start,     w0);
            xp[c] = ldxrow(xb + c * plane, f_start + 1, w0);
        }
    }

    // prefetch weights for the first front (row clamped; unused when !val)
    float wgt[9][4];
    {
        int q0 = f_start - 2 * s;
        int qc = min(max(q0, 0), H_ - 1);
        const float* wp = wb + (size_t)qc * W_ + w0;
#pragma unroll
        for (int j = 0; j < 9; ++j) {
            float4 v = *reinterpret_cast<const float4*>(wp + j * plane);
            wgt[j][0] = v.x; wgt[j][1] = v.y; wgt[j][2] = v.z; wgt[j][3] = v.w;
        }
    }

    for (int f = f_start; f < f_start + NFRONT; ++f) {
        const int q = f - 2 * s;                 // row this wave produces
        const bool rowok = (q >= 0) && (q < H_);
        const bool val = rowok && (f >= vfront); // inputs fully valid

        if (s == 0) {
            // stage 1: inputs from register window
#pragma unroll
            for (int c = 0; c < CPB; ++c) {
                float acc[4] = {0.f, 0.f, 0.f, 0.f};
                if (val) {
                    float rb[3][6];
                    mkrb(xm[c], hasL, hasR, rb[0]);
                    mkrb(xc[c], hasL, hasR, rb[1]);
                    mkrb(xp[c], hasL, hasR, rb[2]);
                    stencil4(wgt, rb, acc);
                }
                *reinterpret_cast<float4*>(&ring[0][q & 3][c][w0]) =
                    make_float4(acc[0], acc[1], acc[2], acc[3]);
            }
            // rotate window; prefetch next front's x row (q+2) pre-barrier
#pragma unroll
            for (int c = 0; c < CPB; ++c) {
                xm[c] = xc[c]; xc[c] = xp[c];
                xp[c] = ldxrow(xb + c * plane, q + 2, w0);
            }
        } else {
            // stages 2..T: inputs from ring[s-1], rows q-1..q+1
#pragma unroll
            for (int c = 0; c < CPB; ++c) {
                float acc[4] = {0.f, 0.f, 0.f, 0.f};
                if (val) {
                    float rb[3][6];
#pragma unroll
                    for (int i = 0; i < 3; ++i) {
                        int p = q - 1 + i;
                        float4 v = (p >= 0 && p < H_)
                            ? *reinterpret_cast<const float4*>(&ring[s - 1][p & 3][c][w0])
                            : zero4();
                        mkrb(v, hasL, hasR, rb[i]);
                    }
                    stencil4(wgt, rb, acc);
                }
                if (s < T_ - 1) {
                    *reinterpret_cast<float4*>(&ring[s][q & 3][c][w0]) =
                        make_float4(acc[0], acc[1], acc[2], acc[3]);
                } else if (val && q >= h0 && q < h0 + CHUNK) {
                    *reinterpret_cast<float4*>(xout + ((size_t)b * C_ + (c0 + c)) * plane +
                                               (size_t)q * W_ + w0) =
                        make_float4(acc[0], acc[1], acc[2], acc[3]);
                }
            }
        }

        // prefetch next front's weights (row q+1, clamped) BEFORE barrier
        float wgtn[9][4];
        {
            int qn = min(max(q + 1, 0), H_ - 1);
            const float* wp = wb + (size_t)qn * W_ + w0;
#pragma unroll
            for (int j = 0; j < 9; ++j) {
                float4 v = *reinterpret_cast<const float4*>(wp + j * plane);
                wgtn[j][0] = v.x; wgtn[j][1] = v.y; wgtn[j][2] = v.z; wgtn[j][3] = v.w;
            }
        }
        __syncthreads();   // front advance: ring writes visible to next front
#pragma unroll
        for (int j = 0; j < 9; ++j) {
            wgt[j][0] = wgtn[j][0]; wgt[j][1] = wgtn[j][1];
            wgt[j][2] = wgtn[j][2]; wgt[j][3] = wgtn[j][3];
        }
    }
}

extern "C" void kernel_launch(void* const* d_in, const int* in_sizes, int n_in,
                              void* d_out, int out_size, void* d_ws, size_t ws_size,
                              hipStream_t stream) {
    const float* x      = (const float*)d_in[0];
    const float* guided = (const float*)d_in[1];
    const float* depth  = (const float*)d_in[2];
    // d_in[3] = prop_time; fixed to 16 by setup_inputs.
    const int DISPATCHES = 4;    // 16 steps, T_=4 per dispatch

    float* xbuf = (float*)d_ws;                                   // 64 MB
    float* wts  = (float*)((char*)d_ws +
                           (size_t)B_ * C_ * H_ * W_ * sizeof(float)); // 18.9 MB
    float* out  = (float*)d_out;

    int total = B_ * H_ * W_;
    hipLaunchKernelGGL(prep_weights_kernel, dim3((total + 255) / 256), dim3(256),
                       0, stream, guided, depth, wts, total);

    dim3 grid(H_ / CHUNK, C_ / CPB, B_), block(64, T_, 1);
    const float* src = x;
    for (int t = 0; t < DISPATCHES; ++t) {
        float* dst = (t == DISPATCHES - 1) ? out : ((t % 2 == 0) ? xbuf : out);
        hipLaunchKernelGGL(prop_stream_kernel, grid, block, 0, stream,
                           src, wts, dst);
        src = dst;
    }
}